// Round 14
// baseline (384.143 us; speedup 1.0000x reference)
//
#include <hip/hip_runtime.h>

#define BATCH 1024
#define NNODE 92
#define FIN   1024
#define FOUT  512

typedef float    f32x4 __attribute__((ext_vector_type(4)));
typedef _Float16 half8 __attribute__((ext_vector_type(8)));
typedef _Float16 half4 __attribute__((ext_vector_type(4)));

__device__ __forceinline__ float lrelu(float x) { return fmaxf(x, 0.2f * x); }

#define BAR_LGKM() do {                                                        \
    asm volatile("s_waitcnt lgkmcnt(0)" ::: "memory");                         \
    __builtin_amdgcn_sched_barrier(0);                                         \
    __builtin_amdgcn_s_barrier();                                              \
  } while (0)

// ---------------------------------------------------------------------------
// prep: WT[n][k] = f16(W[k][n]);  ATp[j][k] = f16(A[k][j]) padded [96][104]
// ---------------------------------------------------------------------------
__global__ __launch_bounds__(256) void prep_kernel(
    const float* __restrict__ W, const float* __restrict__ Am,
    _Float16* __restrict__ WT, _Float16* __restrict__ ATp) {
  int bid = blockIdx.x, t = threadIdx.x;
  if (bid < 64) {
    int n0 = bid * 8;
    for (int it = 0; it < 4; ++it) {
      int k = it * 256 + t;
      const f32x4* src = (const f32x4*)(W + (size_t)k * FOUT + n0);
      f32x4 v0 = src[0], v1 = src[1];
      #pragma unroll
      for (int c = 0; c < 4; ++c) {
        WT[(size_t)(n0 + c) * FIN + k]     = (_Float16)v0[c];
        WT[(size_t)(n0 + 4 + c) * FIN + k] = (_Float16)v1[c];
      }
    }
  } else {
    int j0 = (bid - 64) * 24;
    for (int idx = t; idx < 24 * 104; idx += 256) {
      int jr = idx / 104, k = idx - jr * 104;
      int j = j0 + jr;
      float v = (j < NNODE && k < NNODE) ? Am[k * NNODE + j] : 0.f;
      ATp[j * 104 + k] = (_Float16)v;
    }
  }
}

// ---------------------------------------------------------------------------
// FUSED, 1024 threads, one block per batch (1 block/CU, 159.5 KB LDS).
//  GEMM: X[b] staged in TWO contiguous half-K bursts (xh [96][512] f16,
//    2-KB contiguous row-half reads -- wave reads 1 KB contiguous, the
//    pattern that measured 4.6 TB/s in K2). Per half: 8 barrier-free
//    phases; only B-frag loads (global->reg, L2-resident WT) in flight.
//    Wave tile 96m x 32n (acc[6][2]). 4 GEMM barriers total (was 16).
//  Attention: whT overlays dead xh after the k-loop; fused Wh1/Wh2;
//    e0 -> QK (waves 0-5) -> softmax -> att -> PV (16 waves x 32) -> out.
// LDS map (bytes): xh 0..98303 (GEMM) | whT 0..106495 (post) |
//   at_ 106496 | e0a 126464 | red 146432 | w1s 158720 | w2s 159104.
// ---------------------------------------------------------------------------
__global__ __launch_bounds__(1024, 4) void fused_kernel(
    const float* __restrict__ X, const _Float16* __restrict__ WT,
    const _Float16* __restrict__ ATp, const int* __restrict__ adj,
    const float* __restrict__ av, const float* __restrict__ bias,
    float* __restrict__ out) {
  extern __shared__ char smem[];
  _Float16* xh  = (_Float16*)smem;                  // [96][512] swz (GEMM)
  _Float16* whT = (_Float16*)smem;                  // [512][104] post-GEMM
  _Float16* at_ = (_Float16*)(smem + 106496);       // [96][104]
  _Float16* e0a = (_Float16*)(smem + 126464);       // [96][104]
  float* red = (float*)(smem + 146432);             // [96][32]
  float* w1s = (float*)(smem + 158720);             // [96]
  float* w2s = (float*)(smem + 159104);             // [96]

  int t = threadIdx.x, l = t & 63, w = t >> 6;      // 16 waves
  int b = blockIdx.x;
  const float* Xb = X + (size_t)b * NNODE * FIN;

  // stage map: pass p covers rows p*8 + srow; sk = 16B-chunk in row-half
  int srow = t >> 7, sk = t & 127;

  // B direct-from-global fragment base: n = w*32 + ni*16 + (l&15)
  const _Float16* WTb = WT + (size_t)(w * 32 + (l & 15)) * FIN + (l >> 4) * 8;

  f32x4 zz = {0.f, 0.f, 0.f, 0.f};
  f32x4 acc[6][2];
  #pragma unroll
  for (int mi = 0; mi < 6; ++mi)
    #pragma unroll
    for (int ni = 0; ni < 2; ++ni) acc[mi][ni] = zz;

  half8 bfA[2], bfB[2];

// stage half H: 4 groups x {issue 3 contiguous f32x4 row-half reads,
// convert+swizzled-write}. rows 92..95: clamped read, zero write.
#define STAGE_HALF(H) do {                                                     \
    _Pragma("unroll")                                                          \
    for (int g = 0; g < 4; ++g) {                                              \
      f32x4 v[3];                                                              \
      _Pragma("unroll")                                                        \
      for (int p = 0; p < 3; ++p) {                                            \
        int row = (g * 3 + p) * 8 + srow;                                      \
        int rowc = row < 92 ? row : 91;                                        \
        v[p] = *(const f32x4*)(Xb + (size_t)rowc * FIN + (H) * 512 + sk * 4);  \
      }                                                                        \
      _Pragma("unroll")                                                        \
      for (int p = 0; p < 3; ++p) {                                            \
        int row = (g * 3 + p) * 8 + srow;                                      \
        half4 hh;                                                              \
        if (row < 92) {                                                        \
          hh[0] = (_Float16)v[p][0]; hh[1] = (_Float16)v[p][1];                \
          hh[2] = (_Float16)v[p][2]; hh[3] = (_Float16)v[p][3];                \
        } else {                                                               \
          hh[0] = (_Float16)0.f; hh[1] = (_Float16)0.f;                        \
          hh[2] = (_Float16)0.f; hh[3] = (_Float16)0.f;                        \
        }                                                                      \
        int slotp = (sk >> 1) ^ (row & 7);                                     \
        *(half4*)((char*)xh + row * 1024 + slotp * 16 + (sk & 1) * 8) = hh;    \
      }                                                                        \
    }                                                                          \
  } while (0)

#define F_BFLOAD(DST, KK) do {                                                 \
    int kk_ = (KK) > 992 ? 992 : (KK);                                         \
    _Pragma("unroll")                                                          \
    for (int ni = 0; ni < 2; ++ni)                                             \
      (DST)[ni] = *(const half8*)(WTb + (size_t)(ni * 16) * FIN + kk_);        \
  } while (0)

#define F_MFMA(BF, KT, S) do {                                                 \
    half8 af[6];                                                               \
    _Pragma("unroll")                                                          \
    for (int mi = 0; mi < 6; ++mi) {                                           \
      int row_ = mi * 16 + (l & 15);                                           \
      int slot_ = ((KT) * 8 + (S) * 4 + (l >> 4)) ^ (row_ & 7);                \
      af[mi] = *(const half8*)((const char*)xh + row_ * 1024 + slot_ * 16);    \
    }                                                                          \
    _Pragma("unroll")                                                          \
    for (int mi = 0; mi < 6; ++mi)                                             \
      _Pragma("unroll")                                                        \
      for (int ni = 0; ni < 2; ++ni)                                           \
        acc[mi][ni] = __builtin_amdgcn_mfma_f32_16x16x32_f16(                  \
            af[mi], (BF)[ni], acc[mi][ni], 0, 0, 0);                           \
  } while (0)

// 8 barrier-free phases over xh; bfA enters holding k-block (H*512),
// exits holding ((H+1)*512) (clamped at the very end).
#define GEMM_HALF(H) do {                                                      \
    _Pragma("unroll")                                                          \
    for (int kt = 0; kt < 8; ++kt) {                                           \
      F_BFLOAD(bfB, (H) * 512 + kt * 64 + 32);                                 \
      F_MFMA(bfA, kt, 0);                                                      \
      F_BFLOAD(bfA, (H) * 512 + kt * 64 + 64);                                 \
      F_MFMA(bfB, kt, 1);                                                      \
    }                                                                          \
  } while (0)

  STAGE_HALF(0);
  BAR_LGKM();                 // xh half-0 visible
  F_BFLOAD(bfA, 0);
  GEMM_HALF(0);               // bfA exits with k=512
  BAR_LGKM();                 // all half-0 reads done
  STAGE_HALF(1);
  BAR_LGKM();                 // xh half-1 visible
  GEMM_HALF(1);
  BAR_LGKM();                 // all reads done; xh dead -> whT may overwrite

  // ---- whT write: acc -> whT[C][m] (half4; m-quads aligned)
  #pragma unroll
  for (int mi = 0; mi < 6; ++mi) {
    int m4 = mi * 16 + (l >> 4) * 4;
    #pragma unroll
    for (int ni = 0; ni < 2; ++ni) {
      int C = w * 32 + ni * 16 + (l & 15);
      half4 h;
      h[0] = (_Float16)acc[mi][ni][0]; h[1] = (_Float16)acc[mi][ni][1];
      h[2] = (_Float16)acc[mi][ni][2]; h[3] = (_Float16)acc[mi][ni][3];
      *(half4*)((char*)whT + C * 208 + m4 * 2) = h;
    }
  }

  // ---- Wh1/Wh2 = acc . a : lane partials, shfl-reduce, red[96][32]
  {
    float aC1[2], aC2[2];
    #pragma unroll
    for (int ni = 0; ni < 2; ++ni) {
      int C = w * 32 + ni * 16 + (l & 15);
      aC1[ni] = av[C];
      aC2[ni] = av[FOUT + C];
    }
    float p1[6][4], p2[6][4];
    #pragma unroll
    for (int mi = 0; mi < 6; ++mi)
      #pragma unroll
      for (int r = 0; r < 4; ++r) {
        p1[mi][r] = fmaf(acc[mi][0][r], aC1[0], acc[mi][1][r] * aC1[1]);
        p2[mi][r] = fmaf(acc[mi][0][r], aC2[0], acc[mi][1][r] * aC2[1]);
      }
    #pragma unroll
    for (int mm = 1; mm < 16; mm <<= 1)
      #pragma unroll
      for (int mi = 0; mi < 6; ++mi)
        #pragma unroll
        for (int r = 0; r < 4; ++r) {
          p1[mi][r] += __shfl_xor(p1[mi][r], mm);
          p2[mi][r] += __shfl_xor(p2[mi][r], mm);
        }
    if ((l & 15) == 0) {
      #pragma unroll
      for (int mi = 0; mi < 6; ++mi)
        #pragma unroll
        for (int r = 0; r < 4; ++r) {
          int m = mi * 16 + (l >> 4) * 4 + r;
          red[m * 32 + w * 2]     = p1[mi][r];
          red[m * 32 + w * 2 + 1] = p2[mi][r];
        }
    }
  }
  // ---- stage at_ (1248 half8)
  for (int idx = t; idx < 1248; idx += 1024)
    *(half8*)(at_ + idx * 8) = *(const half8*)(ATp + idx * 8);
  __syncthreads();

  if (t < 96) {
    float s1 = 0.f, s2 = 0.f;
    #pragma unroll
    for (int q = 0; q < 16; ++q) {
      s1 += red[t * 32 + q * 2];
      s2 += red[t * 32 + q * 2 + 1];
    }
    w1s[t] = s1;    // rows 92..95: staged-zero X rows -> 0
    w2s[t] = s2;
  }
  __syncthreads();

  // ---- e0[i][k] = lrelu(Wh1[i]+Wh2[k]), zero-padded [96][104]
  for (int idx = t; idx < 96 * 128; idx += 1024) {
    int i = idx >> 7, k = idx & 127;
    if (k < 104) {
      float v = (i < 92 && k < 92) ? lrelu(w1s[i] + w2s[k]) : 0.f;
      e0a[i * 104 + k] = (_Float16)v;
    }
  }
  BAR_LGKM();

  // ---- QK: e = lrelu(e0 @ A), mask, softmax; att back into e0a (waves 0-5)
  if (w < 6) {
    f32x4 ez = {0.f, 0.f, 0.f, 0.f};
    f32x4 eacc[6];
    #pragma unroll
    for (int ni = 0; ni < 6; ++ni) eacc[ni] = ez;
    #pragma unroll
    for (int ks = 0; ks < 3; ++ks) {
      half8 ea = *(const half8*)((const char*)e0a +
                 (16 * w + (l & 15)) * 208 + ks * 64 + (l >> 4) * 16);
      #pragma unroll
      for (int ni = 0; ni < 6; ++ni) {
        half8 bt = *(const half8*)((const char*)at_ +
                   (16 * ni + (l & 15)) * 208 + ks * 64 + (l >> 4) * 16);
        eacc[ni] = __builtin_amdgcn_mfma_f32_16x16x32_f16(ea, bt, eacc[ni], 0, 0, 0);
      }
    }
    float attv[4][6];
    #pragma unroll
    for (int r = 0; r < 4; ++r) {
      int i = 16 * w + (l >> 4) * 4 + r;
      float s[6]; float m = -3.0e38f;
      #pragma unroll
      for (int ni = 0; ni < 6; ++ni) {
        int j = ni * 16 + (l & 15);
        float e = lrelu(eacc[ni][r]);
        float sv = -3.0e38f;
        if (i < 92 && j < 92) {
          int avj = adj[((size_t)b * NNODE + i) * NNODE + j];
          sv = (avj > 0) ? e : -9.0e15f;
        }
        s[ni] = sv;
        m = fmaxf(m, sv);
      }
      #pragma unroll
      for (int mm = 1; mm < 16; mm <<= 1) m = fmaxf(m, __shfl_xor(m, mm));
      float sum = 0.f; float p[6];
      #pragma unroll
      for (int ni = 0; ni < 6; ++ni) {
        int j = ni * 16 + (l & 15);
        p[ni] = (i < 92 && j < 92) ? __expf(s[ni] - m) : 0.f;
        sum += p[ni];
      }
      #pragma unroll
      for (int mm = 1; mm < 16; mm <<= 1) sum += __shfl_xor(sum, mm);
      float rs = (i < 92) ? (1.0f / sum) : 0.f;
      #pragma unroll
      for (int ni = 0; ni < 6; ++ni) attv[r][ni] = p[ni] * rs;
    }
    #pragma unroll
    for (int r = 0; r < 4; ++r) {
      int i = 16 * w + (l >> 4) * 4 + r;
      #pragma unroll
      for (int ni = 0; ni < 6; ++ni)
        e0a[i * 104 + ni * 16 + (l & 15)] = (_Float16)attv[r][ni];
    }
  }
  BAR_LGKM();   // att visible

  // ---- PV: out = att @ Wh + bias ; single pass, wave w -> 32 f-cols
  {
    int f0 = w * 32;
    half8 bfp[3][2];
    #pragma unroll
    for (int ks = 0; ks < 3; ++ks)
      #pragma unroll
      for (int ni = 0; ni < 2; ++ni)
        bfp[ks][ni] = *(const half8*)((const char*)whT +
            (f0 + ni * 16 + (l & 15)) * 208 + ks * 64 + (l >> 4) * 16);
    f32x4 pz = {0.f, 0.f, 0.f, 0.f};
    f32x4 pacc[6][2];
    #pragma unroll
    for (int mi = 0; mi < 6; ++mi)
      #pragma unroll
      for (int ni = 0; ni < 2; ++ni) pacc[mi][ni] = pz;
    #pragma unroll
    for (int ks = 0; ks < 3; ++ks) {
      half8 af[6];
      #pragma unroll
      for (int mi = 0; mi < 6; ++mi)
        af[mi] = *(const half8*)((const char*)e0a +
                 (16 * mi + (l & 15)) * 208 + ks * 64 + (l >> 4) * 16);
      #pragma unroll
      for (int mi = 0; mi < 6; ++mi)
        #pragma unroll
        for (int ni = 0; ni < 2; ++ni)
          pacc[mi][ni] = __builtin_amdgcn_mfma_f32_16x16x32_f16(
              af[mi], bfp[ks][ni], pacc[mi][ni], 0, 0, 0);
    }
    #pragma unroll
    for (int ni = 0; ni < 2; ++ni) {
      int fcol = f0 + ni * 16 + (l & 15);
      float bv = bias[fcol];
      #pragma unroll
      for (int mi = 0; mi < 6; ++mi)
        #pragma unroll
        for (int r = 0; r < 4; ++r) {
          int i = 16 * mi + (l >> 4) * 4 + r;
          if (i < 92)
            out[((size_t)b * NNODE + i) * FOUT + fcol] = pacc[mi][ni][r] + bv;
        }
    }
  }
}

// ---------------------------------------------------------------------------
extern "C" void kernel_launch(void* const* d_in, const int* in_sizes, int n_in,
                              void* d_out, int out_size, void* d_ws, size_t ws_size,
                              hipStream_t stream) {
  (void)in_sizes; (void)n_in; (void)out_size; (void)ws_size;
  const float* X    = (const float*)d_in[0];
  const int*   adj  = (const int*)d_in[1];
  const float* W    = (const float*)d_in[2];
  const float* av   = (const float*)d_in[3];
  const float* Am   = (const float*)d_in[4];
  const float* bias = (const float*)d_in[5];
  float* out = (float*)d_out;
  char* ws = (char*)d_ws;

  _Float16* WT  = (_Float16*)(ws);              // 1,048,576 B
  _Float16* ATp = (_Float16*)(ws + 1048576);    //    19,968 B

  prep_kernel<<<68, 256, 0, stream>>>(W, Am, WT, ATp);
  hipFuncSetAttribute((const void*)fused_kernel,
                      hipFuncAttributeMaxDynamicSharedMemorySize, 159488);
  fused_kernel<<<1024, 1024, 159488, stream>>>(X, WT, ATp, adj, av, bias, out);
}

// Round 15
// 307.043 us; speedup vs baseline: 1.2511x; 1.2511x over previous
//
#include <hip/hip_runtime.h>

#define BATCH 1024
#define NNODE 92
#define FIN   1024
#define FOUT  512

typedef float    f32x4 __attribute__((ext_vector_type(4)));
typedef _Float16 half8 __attribute__((ext_vector_type(8)));
typedef _Float16 half4 __attribute__((ext_vector_type(4)));

__device__ __forceinline__ float lrelu(float x) { return fmaxf(x, 0.2f * x); }

#define BAR_LGKM() do {                                                        \
    asm volatile("s_waitcnt lgkmcnt(0)" ::: "memory");                         \
    __builtin_amdgcn_sched_barrier(0);                                         \
    __builtin_amdgcn_s_barrier();                                              \
  } while (0)

// ---------------------------------------------------------------------------
// prep: WT[n][k] = f16(W[k][n]);  ATp[j][k] = f16(A[k][j]) padded [96][104]
// ---------------------------------------------------------------------------
__global__ __launch_bounds__(256) void prep_kernel(
    const float* __restrict__ W, const float* __restrict__ Am,
    _Float16* __restrict__ WT, _Float16* __restrict__ ATp) {
  int bid = blockIdx.x, t = threadIdx.x;
  if (bid < 64) {
    int n0 = bid * 8;
    for (int it = 0; it < 4; ++it) {
      int k = it * 256 + t;
      const f32x4* src = (const f32x4*)(W + (size_t)k * FOUT + n0);
      f32x4 v0 = src[0], v1 = src[1];
      #pragma unroll
      for (int c = 0; c < 4; ++c) {
        WT[(size_t)(n0 + c) * FIN + k]     = (_Float16)v0[c];
        WT[(size_t)(n0 + 4 + c) * FIN + k] = (_Float16)v1[c];
      }
    }
  } else {
    int j0 = (bid - 64) * 24;
    for (int idx = t; idx < 24 * 104; idx += 256) {
      int jr = idx / 104, k = idx - jr * 104;
      int j = j0 + jr;
      float v = (j < NNODE && k < NNODE) ? Am[k * NNODE + j] : 0.f;
      ATp[j * 104 + k] = (_Float16)v;
    }
  }
}

// ---------------------------------------------------------------------------
// FUSED, 512 threads (8 waves), one block per batch, 1 block/CU.
//  Identical to the passing R11 kernel EXCEPT the per-phase VMEM issue
//  order: B-fragment loads are issued BEFORE the X prefetch, so vmcnt's
//  in-order drain semantics no longer force every B-wait to drain the
//  chip-wide X HBM burst. Queue per phase: [B(kt,S1), B(kt+1,S0), X(kt+2)].
//  GEMM: Wh[b] = X[b] @ W into LDS whT[512][104]; 16 phases BK=64; wave
//    tile 96m x 64n (acc[6][4]); X dbuf-staged; B global->reg from L2 WT.
//  Attention: fused Wh1/Wh2, at_ overlays dead xs, e0 -> QK (waves 0-5) ->
//    softmax -> att -> PV (2 passes x 32 cols) -> out.
// LDS map (bytes): whT 0 | xs0 106496 | xs1 118784 | at_ overlays 106496 |
//   e0a 131072 | red 151040 | w1s 157184 | w2s 157568 | total 157952.
// ---------------------------------------------------------------------------
__global__ __launch_bounds__(512, 2) void fused_kernel(
    const float* __restrict__ X, const _Float16* __restrict__ WT,
    const _Float16* __restrict__ ATp, const int* __restrict__ adj,
    const float* __restrict__ av, const float* __restrict__ bias,
    float* __restrict__ out) {
  extern __shared__ char smem[];
  _Float16* whT = (_Float16*)smem;                  // [512][104]
  _Float16* xs0 = (_Float16*)(smem + 106496);       // [96][64] swz
  _Float16* xs1 = (_Float16*)(smem + 118784);
  _Float16* at_ = (_Float16*)(smem + 106496);       // overlays xs after GEMM
  _Float16* e0a = (_Float16*)(smem + 131072);       // [96][104]
  float* red = (float*)(smem + 151040);             // [96][16]
  float* w1s = (float*)(smem + 157184);             // [96]
  float* w2s = (float*)(smem + 157568);              // [96]

  int t = threadIdx.x, l = t & 63, w = t >> 6;
  int b = blockIdx.x;
  const float* Xb = X + (size_t)b * NNODE * FIN;

  // ---- X staging maps: idx = c*512+t, row = idx>>4 (0..95), kq = idx&15
  int xrow[3], xwoff[3];
  bool xok[3];
  #pragma unroll
  for (int c = 0; c < 3; ++c) {
    int idx = c * 512 + t;
    int row = idx >> 4, kq = idx & 15;
    xrow[c] = (row < 92) ? row : 91;
    xok[c] = (row < 92);
    xwoff[c] = row * 128 + (((kq >> 1) ^ (row & 7)) << 4) + (kq & 1) * 8;
  }

  // ---- B direct-from-global fragment base
  const _Float16* WTb = WT + (size_t)(w * 64 + (l & 15)) * FIN + (l >> 4) * 8;

  f32x4 zz = {0.f, 0.f, 0.f, 0.f};
  f32x4 acc[6][4];
  #pragma unroll
  for (int mi = 0; mi < 6; ++mi)
    #pragma unroll
    for (int ni = 0; ni < 4; ++ni) acc[mi][ni] = zz;

  f32x4 xvA[3], xvB[3];
  half8 bfA[4], bfB[4];

#define F_XISSUE(XV, KT) do {                                                  \
    int ktc_ = (KT) > 15 ? 15 : (KT);                                          \
    _Pragma("unroll")                                                          \
    for (int c = 0; c < 3; ++c) {                                              \
      int idx_ = c * 512 + t;                                                  \
      (XV)[c] = *(const f32x4*)(Xb + (size_t)xrow[c] * FIN + ktc_ * 64 +       \
                                (idx_ & 15) * 4);                              \
    }                                                                          \
  } while (0)

#define F_XCONV(BUF, XV) do {                                                  \
    _Pragma("unroll")                                                          \
    for (int c = 0; c < 3; ++c) {                                              \
      half4 h;                                                                 \
      if (xok[c]) {                                                            \
        h[0] = (_Float16)(XV)[c][0]; h[1] = (_Float16)(XV)[c][1];              \
        h[2] = (_Float16)(XV)[c][2]; h[3] = (_Float16)(XV)[c][3];              \
      } else {                                                                 \
        h[0] = (_Float16)0.f; h[1] = (_Float16)0.f;                            \
        h[2] = (_Float16)0.f; h[3] = (_Float16)0.f;                            \
      }                                                                        \
      *(half4*)((char*)(BUF) + xwoff[c]) = h;                                  \
    }                                                                          \
  } while (0)

#define F_BFLOAD(DST, KT, S) do {                                              \
    int ktc_ = (KT) > 15 ? 15 : (KT);                                          \
    _Pragma("unroll")                                                          \
    for (int ni = 0; ni < 4; ++ni)                                             \
      (DST)[ni] = *(const half8*)(WTb + (size_t)(ni * 16) * FIN +              \
                                  ktc_ * 64 + (S) * 32);                       \
  } while (0)

#define F_MFMA(XSBUF, BF, S) do {                                              \
    half8 af[6];                                                               \
    _Pragma("unroll")                                                          \
    for (int mi = 0; mi < 6; ++mi) {                                           \
      int row_ = mi * 16 + (l & 15);                                           \
      int slot_ = (((S) * 4 + (l >> 4)) ^ (row_ & 7));                         \
      af[mi] = *(const half8*)((const char*)(XSBUF) + row_ * 128 +             \
                               slot_ * 16);                                    \
    }                                                                          \
    _Pragma("unroll")                                                          \
    for (int mi = 0; mi < 6; ++mi)                                             \
      _Pragma("unroll")                                                        \
      for (int ni = 0; ni < 4; ++ni)                                           \
        acc[mi][ni] = __builtin_amdgcn_mfma_f32_16x16x32_f16(                  \
            af[mi], (BF)[ni], acc[mi][ni], 0, 0, 0);                           \
  } while (0)

// phase KT: B loads FIRST in the vmem queue, X prefetch LAST.
// Queue: [bfB(KT,S1), bfA(KT+1,S0), X(KT+2)] -> MFMA's B-waits never
// drain the newest X burst; XCONV at end of NEXT phase drains X(KT+2)
// after it has had a full phase in flight.
#define F_PHASE(KT, XN, XP, CUR, NXT) do {                                     \
    F_BFLOAD(bfB, (KT), 1);                                                    \
    F_MFMA(CUR, bfA, 0);                                                       \
    F_BFLOAD(bfA, (KT) + 1, 0);                                                \
    F_MFMA(CUR, bfB, 1);                                                       \
    F_XISSUE(XN, (KT) + 2);                                                    \
    F_XCONV(NXT, XP);                                                          \
    BAR_LGKM();                                                                \
  } while (0)

  // prologue: X(0) staged; queue leaving prologue = [bfA(0,0), X(1)]
  F_XISSUE(xvA, 0);
  F_XCONV(xs0, xvA);              // waits X(0) only
  F_BFLOAD(bfA, 0, 0);
  F_XISSUE(xvA, 1);
  BAR_LGKM();

  #pragma unroll 1
  for (int kt = 0; kt < 16; kt += 2) {
    F_PHASE(kt + 0, xvB, xvA, xs0, xs1);
    F_PHASE(kt + 1, xvA, xvB, xs1, xs0);
  }

  // ---- whT write: acc -> whT[C][m] (half4, m-quads aligned)
  #pragma unroll
  for (int mi = 0; mi < 6; ++mi) {
    int m4 = mi * 16 + (l >> 4) * 4;
    #pragma unroll
    for (int ni = 0; ni < 4; ++ni) {
      int C = w * 64 + ni * 16 + (l & 15);
      half4 h;
      h[0] = (_Float16)acc[mi][ni][0]; h[1] = (_Float16)acc[mi][ni][1];
      h[2] = (_Float16)acc[mi][ni][2]; h[3] = (_Float16)acc[mi][ni][3];
      *(half4*)((char*)whT + C * 208 + m4 * 2) = h;
    }
  }

  // ---- Wh1/Wh2 = acc . a : per-lane over owned C, shfl-reduce, red[96][16]
  {
    float aC1[4], aC2[4];
    #pragma unroll
    for (int ni = 0; ni < 4; ++ni) {
      int C = w * 64 + ni * 16 + (l & 15);
      aC1[ni] = av[C];
      aC2[ni] = av[FOUT + C];
    }
    float p1[6][4], p2[6][4];
    #pragma unroll
    for (int mi = 0; mi < 6; ++mi)
      #pragma unroll
      for (int r = 0; r < 4; ++r) {
        float s1 = 0.f, s2 = 0.f;
        #pragma unroll
        for (int ni = 0; ni < 4; ++ni) {
          s1 = fmaf(acc[mi][ni][r], aC1[ni], s1);
          s2 = fmaf(acc[mi][ni][r], aC2[ni], s2);
        }
        p1[mi][r] = s1; p2[mi][r] = s2;
      }
    #pragma unroll
    for (int mm = 1; mm < 16; mm <<= 1)
      #pragma unroll
      for (int mi = 0; mi < 6; ++mi)
        #pragma unroll
        for (int r = 0; r < 4; ++r) {
          p1[mi][r] += __shfl_xor(p1[mi][r], mm);
          p2[mi][r] += __shfl_xor(p2[mi][r], mm);
        }
    if ((l & 15) == 0) {
      #pragma unroll
      for (int mi = 0; mi < 6; ++mi)
        #pragma unroll
        for (int r = 0; r < 4; ++r) {
          int m = mi * 16 + (l >> 4) * 4 + r;
          red[m * 16 + w * 2]     = p1[mi][r];
          red[m * 16 + w * 2 + 1] = p2[mi][r];
        }
    }
  }
  // ---- stage at_ into dead xs region (96*104 f16 = 1248 half8)
  for (int idx = t; idx < 1248; idx += 512)
    *(half8*)(at_ + idx * 8) = *(const half8*)(ATp + idx * 8);
  __syncthreads();

  if (t < 96) {
    float s1 = 0.f, s2 = 0.f;
    #pragma unroll
    for (int q = 0; q < 8; ++q) {
      s1 += red[t * 16 + q * 2];
      s2 += red[t * 16 + q * 2 + 1];
    }
    w1s[t] = s1;    // rows 92..95 are 0 (zeroed X rows)
    w2s[t] = s2;
  }
  __syncthreads();

  // ---- e0[i][k] = lrelu(Wh1[i]+Wh2[k]), zero-padded [96][104]
  for (int idx = t; idx < 96 * 128; idx += 512) {
    int i = idx >> 7, k = idx & 127;
    if (k < 104) {
      float v = (i < 92 && k < 92) ? lrelu(w1s[i] + w2s[k]) : 0.f;
      e0a[i * 104 + k] = (_Float16)v;
    }
  }
  BAR_LGKM();

  // ---- QK: e = lrelu(e0 @ A), mask, softmax; att back into e0a (waves 0-5)
  if (w < 6) {
    f32x4 ez = {0.f, 0.f, 0.f, 0.f};
    f32x4 eacc[6];
    #pragma unroll
    for (int ni = 0; ni < 6; ++ni) eacc[ni] = ez;
    #pragma unroll
    for (int ks = 0; ks < 3; ++ks) {
      half8 ea = *(const half8*)((const char*)e0a +
                 (16 * w + (l & 15)) * 208 + ks * 64 + (l >> 4) * 16);
      #pragma unroll
      for (int ni = 0; ni < 6; ++ni) {
        half8 bt = *(const half8*)((const char*)at_ +
                   (16 * ni + (l & 15)) * 208 + ks * 64 + (l >> 4) * 16);
        eacc[ni] = __builtin_amdgcn_mfma_f32_16x16x32_f16(ea, bt, eacc[ni], 0, 0, 0);
      }
    }
    float attv[4][6];
    #pragma unroll
    for (int r = 0; r < 4; ++r) {
      int i = 16 * w + (l >> 4) * 4 + r;
      float s[6]; float m = -3.0e38f;
      #pragma unroll
      for (int ni = 0; ni < 6; ++ni) {
        int j = ni * 16 + (l & 15);
        float e = lrelu(eacc[ni][r]);
        float sv = -3.0e38f;
        if (i < 92 && j < 92) {
          int avj = adj[((size_t)b * NNODE + i) * NNODE + j];
          sv = (avj > 0) ? e : -9.0e15f;
        }
        s[ni] = sv;
        m = fmaxf(m, sv);
      }
      #pragma unroll
      for (int mm = 1; mm < 16; mm <<= 1) m = fmaxf(m, __shfl_xor(m, mm));
      float sum = 0.f; float p[6];
      #pragma unroll
      for (int ni = 0; ni < 6; ++ni) {
        int j = ni * 16 + (l & 15);
        p[ni] = (i < 92 && j < 92) ? __expf(s[ni] - m) : 0.f;
        sum += p[ni];
      }
      #pragma unroll
      for (int mm = 1; mm < 16; mm <<= 1) sum += __shfl_xor(sum, mm);
      float rs = (i < 92) ? (1.0f / sum) : 0.f;
      #pragma unroll
      for (int ni = 0; ni < 6; ++ni) attv[r][ni] = p[ni] * rs;
    }
    #pragma unroll
    for (int r = 0; r < 4; ++r) {
      int i = 16 * w + (l >> 4) * 4 + r;
      #pragma unroll
      for (int ni = 0; ni < 6; ++ni)
        e0a[i * 104 + ni * 16 + (l & 15)] = (_Float16)attv[r][ni];
    }
  }
  BAR_LGKM();   // att visible

  // ---- PV: out = att @ Wh + bias ; wave w: 2 passes of 32 f-cols
  #pragma unroll 1
  for (int pp = 0; pp < 2; ++pp) {
    int f0 = pp * 256 + w * 32;
    half8 bfp[3][2];
    #pragma unroll
    for (int ks = 0; ks < 3; ++ks)
      #pragma unroll
      for (int ni = 0; ni < 2; ++ni)
        bfp[ks][ni] = *(const half8*)((const char*)whT +
            (f0 + ni * 16 + (l & 15)) * 208 + ks * 64 + (l >> 4) * 16);
    f32x4 pz = {0.f, 0.f, 0.f, 0.f};
    f32x4 pacc[6][2];
    #pragma unroll
    for (int mi = 0; mi < 6; ++mi)
      #pragma unroll
      for (int ni = 0; ni < 2; ++ni) pacc[mi][ni] = pz;
    #pragma unroll
    for (int ks = 0; ks < 3; ++ks) {
      half8 af[6];
      #pragma unroll
      for (int mi = 0; mi < 6; ++mi)
        af[mi] = *(const half8*)((const char*)e0a +
                 (16 * mi + (l & 15)) * 208 + ks * 64 + (l >> 4) * 16);
      #pragma unroll
      for (int mi = 0; mi < 6; ++mi)
        #pragma unroll
        for (int ni = 0; ni < 2; ++ni)
          pacc[mi][ni] = __builtin_amdgcn_mfma_f32_16x16x32_f16(
              af[mi], bfp[ks][ni], pacc[mi][ni], 0, 0, 0);
    }
    #pragma unroll
    for (int ni = 0; ni < 2; ++ni) {
      int fcol = f0 + ni * 16 + (l & 15);
      float bv = bias[fcol];
      #pragma unroll
      for (int mi = 0; mi < 6; ++mi)
        #pragma unroll
        for (int r = 0; r < 4; ++r) {
          int i = 16 * mi + (l >> 4) * 4 + r;
          if (i < 92)
            out[((size_t)b * NNODE + i) * FOUT + fcol] = pacc[mi][ni][r] + bv;
        }
    }
  }
}

// ---------------------------------------------------------------------------
extern "C" void kernel_launch(void* const* d_in, const int* in_sizes, int n_in,
                              void* d_out, int out_size, void* d_ws, size_t ws_size,
                              hipStream_t stream) {
  (void)in_sizes; (void)n_in; (void)out_size; (void)ws_size;
  const float* X    = (const float*)d_in[0];
  const int*   adj  = (const int*)d_in[1];
  const float* W    = (const float*)d_in[2];
  const float* av   = (const float*)d_in[3];
  const float* Am   = (const float*)d_in[4];
  const float* bias = (const float*)d_in[5];
  float* out = (float*)d_out;
  char* ws = (char*)d_ws;

  _Float16* WT  = (_Float16*)(ws);              // 1,048,576 B
  _Float16* ATp = (_Float16*)(ws + 1048576);    //    19,968 B

  prep_kernel<<<68, 256, 0, stream>>>(W, Am, WT, ATp);
  hipFuncSetAttribute((const void*)fused_kernel,
                      hipFuncAttributeMaxDynamicSharedMemorySize, 157952);
  fused_kernel<<<1024, 512, 157952, stream>>>(X, WT, ATp, adj, av, bias, out);
}

// Round 16
// 241.017 us; speedup vs baseline: 1.5938x; 1.2739x over previous
//
#include <hip/hip_runtime.h>

#define BATCH 1024
#define NNODE 92
#define FIN   1024
#define FOUT  512

typedef float    f32x4 __attribute__((ext_vector_type(4)));
typedef _Float16 half8 __attribute__((ext_vector_type(8)));
typedef _Float16 half4 __attribute__((ext_vector_type(4)));

__device__ __forceinline__ float lrelu(float x) { return fmaxf(x, 0.2f * x); }

#define BAR_LGKM() do {                                                        \
    asm volatile("s_waitcnt lgkmcnt(0)" ::: "memory");                         \
    __builtin_amdgcn_sched_barrier(0);                                         \
    __builtin_amdgcn_s_barrier();                                              \
  } while (0)

// ---------------------------------------------------------------------------
// prep: WT[n][k] = f16(W[k][n]);  ATp[j][k] = f16(A[k][j]) padded [96][104]
// ---------------------------------------------------------------------------
__global__ __launch_bounds__(256) void prep_kernel(
    const float* __restrict__ W, const float* __restrict__ Am,
    _Float16* __restrict__ WT, _Float16* __restrict__ ATp) {
  int bid = blockIdx.x, t = threadIdx.x;
  if (bid < 64) {
    int n0 = bid * 8;
    for (int it = 0; it < 4; ++it) {
      int k = it * 256 + t;
      const f32x4* src = (const f32x4*)(W + (size_t)k * FOUT + n0);
      f32x4 v0 = src[0], v1 = src[1];
      #pragma unroll
      for (int c = 0; c < 4; ++c) {
        WT[(size_t)(n0 + c) * FIN + k]     = (_Float16)v0[c];
        WT[(size_t)(n0 + 4 + c) * FIN + k] = (_Float16)v1[c];
      }
    }
  } else {
    int j0 = (bid - 64) * 24;
    for (int idx = t; idx < 24 * 104; idx += 256) {
      int jr = idx / 104, k = idx - jr * 104;
      int j = j0 + jr;
      float v = (j < NNODE && k < NNODE) ? Am[k * NNODE + j] : 0.f;
      ATp[j * 104 + k] = (_Float16)v;
    }
  }
}

// ---------------------------------------------------------------------------
// FUSED, 512 threads (8 waves), one block per batch, 1 block/CU.
//  R15 base + three latency-burial edits:
//   (1) B-fragments preloaded a FULL phase ahead (4 reg sets, rotated) --
//       MFMA never waits on vmem; per-phase queue [B(kt+1)x2, X(kt+2)].
//   (2) adj prefetched into regs right after the GEMM loop (clamped),
//       consumed by softmax ~5000 cyc later.
//   (3) at_ stage split: global loads issued with adj, LDS writes late.
//  GEMM: Wh[b] = X[b] @ W into LDS whT[512][104]; 16 phases BK=64; wave
//    tile 96m x 64n (acc[6][4]); X dbuf-staged; B global->reg from L2 WT.
//  Attention: fused Wh1/Wh2, at_ overlays dead xs, e0 -> QK (waves 0-5) ->
//    softmax -> att -> PV (2 passes x 32 cols) -> out.
// LDS map (bytes): whT 0 | xs0 106496 | xs1 118784 | at_ overlays 106496 |
//   e0a 131072 | red 151040 | w1s 157184 | w2s 157568 | total 157952.
// ---------------------------------------------------------------------------
__global__ __launch_bounds__(512, 2) void fused_kernel(
    const float* __restrict__ X, const _Float16* __restrict__ WT,
    const _Float16* __restrict__ ATp, const int* __restrict__ adj,
    const float* __restrict__ av, const float* __restrict__ bias,
    float* __restrict__ out) {
  extern __shared__ char smem[];
  _Float16* whT = (_Float16*)smem;                  // [512][104]
  _Float16* xs0 = (_Float16*)(smem + 106496);       // [96][64] swz
  _Float16* xs1 = (_Float16*)(smem + 118784);
  _Float16* at_ = (_Float16*)(smem + 106496);       // overlays xs after GEMM
  _Float16* e0a = (_Float16*)(smem + 131072);       // [96][104]
  float* red = (float*)(smem + 151040);             // [96][16]
  float* w1s = (float*)(smem + 157184);             // [96]
  float* w2s = (float*)(smem + 157568);             // [96]

  int t = threadIdx.x, l = t & 63, w = t >> 6;
  int b = blockIdx.x;
  const float* Xb = X + (size_t)b * NNODE * FIN;

  // ---- X staging maps: idx = c*512+t, row = idx>>4 (0..95), kq = idx&15
  int xrow[3], xwoff[3];
  bool xok[3];
  #pragma unroll
  for (int c = 0; c < 3; ++c) {
    int idx = c * 512 + t;
    int row = idx >> 4, kq = idx & 15;
    xrow[c] = (row < 92) ? row : 91;
    xok[c] = (row < 92);
    xwoff[c] = row * 128 + (((kq >> 1) ^ (row & 7)) << 4) + (kq & 1) * 8;
  }

  // ---- B direct-from-global fragment base
  const _Float16* WTb = WT + (size_t)(w * 64 + (l & 15)) * FIN + (l >> 4) * 8;

  f32x4 zz = {0.f, 0.f, 0.f, 0.f};
  f32x4 acc[6][4];
  #pragma unroll
  for (int mi = 0; mi < 6; ++mi)
    #pragma unroll
    for (int ni = 0; ni < 4; ++ni) acc[mi][ni] = zz;

  f32x4 xvA[3], xvB[3];
  half8 bf0[4], bf1[4], bf2[4], bf3[4];

#define F_XISSUE(XV, KT) do {                                                  \
    int ktc_ = (KT) > 15 ? 15 : (KT);                                          \
    _Pragma("unroll")                                                          \
    for (int c = 0; c < 3; ++c) {                                              \
      int idx_ = c * 512 + t;                                                  \
      (XV)[c] = *(const f32x4*)(Xb + (size_t)xrow[c] * FIN + ktc_ * 64 +       \
                                (idx_ & 15) * 4);                              \
    }                                                                          \
  } while (0)

#define F_XCONV(BUF, XV) do {                                                  \
    _Pragma("unroll")                                                          \
    for (int c = 0; c < 3; ++c) {                                              \
      half4 h;                                                                 \
      if (xok[c]) {                                                            \
        h[0] = (_Float16)(XV)[c][0]; h[1] = (_Float16)(XV)[c][1];              \
        h[2] = (_Float16)(XV)[c][2]; h[3] = (_Float16)(XV)[c][3];              \
      } else {                                                                 \
        h[0] = (_Float16)0.f; h[1] = (_Float16)0.f;                            \
        h[2] = (_Float16)0.f; h[3] = (_Float16)0.f;                            \
      }                                                                        \
      *(half4*)((char*)(BUF) + xwoff[c]) = h;                                  \
    }                                                                          \
  } while (0)

#define F_BFLOAD(DST, KT, S) do {                                              \
    int ktc_ = (KT) > 15 ? 15 : (KT);                                          \
    _Pragma("unroll")                                                          \
    for (int ni = 0; ni < 4; ++ni)                                             \
      (DST)[ni] = *(const half8*)(WTb + (size_t)(ni * 16) * FIN +              \
                                  ktc_ * 64 + (S) * 32);                       \
  } while (0)

#define F_MFMA(XSBUF, BF, S) do {                                              \
    half8 af[6];                                                               \
    _Pragma("unroll")                                                          \
    for (int mi = 0; mi < 6; ++mi) {                                           \
      int row_ = mi * 16 + (l & 15);                                           \
      int slot_ = (((S) * 4 + (l >> 4)) ^ (row_ & 7));                         \
      af[mi] = *(const half8*)((const char*)(XSBUF) + row_ * 128 +             \
                               slot_ * 16);                                    \
    }                                                                          \
    _Pragma("unroll")                                                          \
    for (int mi = 0; mi < 6; ++mi)                                             \
      _Pragma("unroll")                                                        \
      for (int ni = 0; ni < 4; ++ni)                                           \
        acc[mi][ni] = __builtin_amdgcn_mfma_f32_16x16x32_f16(                  \
            af[mi], (BF)[ni], acc[mi][ni], 0, 0, 0);                           \
  } while (0)

// phase KT: preload NEXT phase's B (both halves), then X(KT+2); MFMA uses
// the CURRENT sets loaded a full phase ago (fully resident -- no vmem wait).
#define F_PHASE(KT, XN, XP, CUR, NXT, BC0, BC1, BN0, BN1) do {                 \
    F_BFLOAD(BN0, (KT) + 1, 0);                                                \
    F_BFLOAD(BN1, (KT) + 1, 1);                                                \
    F_XISSUE(XN, (KT) + 2);                                                    \
    F_MFMA(CUR, BC0, 0);                                                       \
    F_MFMA(CUR, BC1, 1);                                                       \
    F_XCONV(NXT, XP);                                                          \
    BAR_LGKM();                                                                \
  } while (0)

  // prologue: X(0) staged; bf0/bf1 = tile 0; X(1) in flight
  F_XISSUE(xvA, 0);
  F_XCONV(xs0, xvA);              // waits X(0) only
  F_BFLOAD(bf0, 0, 0);
  F_BFLOAD(bf1, 0, 1);
  F_XISSUE(xvA, 1);
  BAR_LGKM();

  #pragma unroll 1
  for (int kt = 0; kt < 16; kt += 2) {
    F_PHASE(kt + 0, xvB, xvA, xs0, xs1, bf0, bf1, bf2, bf3);
    F_PHASE(kt + 1, xvA, xvB, xs1, xs0, bf2, bf3, bf0, bf1);
  }

  // ---- adj prefetch into regs (consumed by softmax much later)
  int adjv[4][6];
  if (w < 6) {
    #pragma unroll
    for (int r = 0; r < 4; ++r) {
      int i = 16 * w + (l >> 4) * 4 + r;
      int ic = (i < 92) ? i : 91;
      #pragma unroll
      for (int ni = 0; ni < 6; ++ni) {
        int j = ni * 16 + (l & 15);
        int jc = (j < 92) ? j : 91;
        adjv[r][ni] = adj[((size_t)b * NNODE + ic) * NNODE + jc];
      }
    }
  }
  // ---- at_ stage: ISSUE loads now, write to LDS later
  half8 atv[3];
  bool aok2 = (t < 224);
  atv[0] = *(const half8*)(ATp + (size_t)t * 8);
  atv[1] = *(const half8*)(ATp + (size_t)(512 + t) * 8);
  if (aok2) atv[2] = *(const half8*)(ATp + (size_t)(1024 + t) * 8);

  // ---- whT write: acc -> whT[C][m] (half4, m-quads aligned)
  #pragma unroll
  for (int mi = 0; mi < 6; ++mi) {
    int m4 = mi * 16 + (l >> 4) * 4;
    #pragma unroll
    for (int ni = 0; ni < 4; ++ni) {
      int C = w * 64 + ni * 16 + (l & 15);
      half4 h;
      h[0] = (_Float16)acc[mi][ni][0]; h[1] = (_Float16)acc[mi][ni][1];
      h[2] = (_Float16)acc[mi][ni][2]; h[3] = (_Float16)acc[mi][ni][3];
      *(half4*)((char*)whT + C * 208 + m4 * 2) = h;
    }
  }

  // ---- Wh1/Wh2 = acc . a : per-lane over owned C, shfl-reduce, red[96][16]
  {
    float aC1[4], aC2[4];
    #pragma unroll
    for (int ni = 0; ni < 4; ++ni) {
      int C = w * 64 + ni * 16 + (l & 15);
      aC1[ni] = av[C];
      aC2[ni] = av[FOUT + C];
    }
    float p1[6][4], p2[6][4];
    #pragma unroll
    for (int mi = 0; mi < 6; ++mi)
      #pragma unroll
      for (int r = 0; r < 4; ++r) {
        float s1 = 0.f, s2 = 0.f;
        #pragma unroll
        for (int ni = 0; ni < 4; ++ni) {
          s1 = fmaf(acc[mi][ni][r], aC1[ni], s1);
          s2 = fmaf(acc[mi][ni][r], aC2[ni], s2);
        }
        p1[mi][r] = s1; p2[mi][r] = s2;
      }
    #pragma unroll
    for (int mm = 1; mm < 16; mm <<= 1)
      #pragma unroll
      for (int mi = 0; mi < 6; ++mi)
        #pragma unroll
        for (int r = 0; r < 4; ++r) {
          p1[mi][r] += __shfl_xor(p1[mi][r], mm);
          p2[mi][r] += __shfl_xor(p2[mi][r], mm);
        }
    if ((l & 15) == 0) {
      #pragma unroll
      for (int mi = 0; mi < 6; ++mi)
        #pragma unroll
        for (int r = 0; r < 4; ++r) {
          int m = mi * 16 + (l >> 4) * 4 + r;
          red[m * 16 + w * 2]     = p1[mi][r];
          red[m * 16 + w * 2 + 1] = p2[mi][r];
        }
    }
  }
  // ---- at_ LDS writes (loads have been in flight across whT+reduction)
  *(half8*)(at_ + (size_t)t * 8) = atv[0];
  *(half8*)(at_ + (size_t)(512 + t) * 8) = atv[1];
  if (aok2) *(half8*)(at_ + (size_t)(1024 + t) * 8) = atv[2];
  __syncthreads();

  if (t < 96) {
    float s1 = 0.f, s2 = 0.f;
    #pragma unroll
    for (int q = 0; q < 8; ++q) {
      s1 += red[t * 16 + q * 2];
      s2 += red[t * 16 + q * 2 + 1];
    }
    w1s[t] = s1;    // rows 92..95 are 0 (zeroed X rows)
    w2s[t] = s2;
  }
  __syncthreads();

  // ---- e0[i][k] = lrelu(Wh1[i]+Wh2[k]), zero-padded [96][104]
  for (int idx = t; idx < 96 * 128; idx += 512) {
    int i = idx >> 7, k = idx & 127;
    if (k < 104) {
      float v = (i < 92 && k < 92) ? lrelu(w1s[i] + w2s[k]) : 0.f;
      e0a[i * 104 + k] = (_Float16)v;
    }
  }
  BAR_LGKM();

  // ---- QK: e = lrelu(e0 @ A), mask (adjv regs), softmax; att -> e0a
  if (w < 6) {
    f32x4 ez = {0.f, 0.f, 0.f, 0.f};
    f32x4 eacc[6];
    #pragma unroll
    for (int ni = 0; ni < 6; ++ni) eacc[ni] = ez;
    #pragma unroll
    for (int ks = 0; ks < 3; ++ks) {
      half8 ea = *(const half8*)((const char*)e0a +
                 (16 * w + (l & 15)) * 208 + ks * 64 + (l >> 4) * 16);
      #pragma unroll
      for (int ni = 0; ni < 6; ++ni) {
        half8 bt = *(const half8*)((const char*)at_ +
                   (16 * ni + (l & 15)) * 208 + ks * 64 + (l >> 4) * 16);
        eacc[ni] = __builtin_amdgcn_mfma_f32_16x16x32_f16(ea, bt, eacc[ni], 0, 0, 0);
      }
    }
    float attv[4][6];
    #pragma unroll
    for (int r = 0; r < 4; ++r) {
      int i = 16 * w + (l >> 4) * 4 + r;
      float s[6]; float m = -3.0e38f;
      #pragma unroll
      for (int ni = 0; ni < 6; ++ni) {
        int j = ni * 16 + (l & 15);
        float e = lrelu(eacc[ni][r]);
        float sv = -3.0e38f;
        if (i < 92 && j < 92)
          sv = (adjv[r][ni] > 0) ? e : -9.0e15f;
        s[ni] = sv;
        m = fmaxf(m, sv);
      }
      #pragma unroll
      for (int mm = 1; mm < 16; mm <<= 1) m = fmaxf(m, __shfl_xor(m, mm));
      float sum = 0.f; float p[6];
      #pragma unroll
      for (int ni = 0; ni < 6; ++ni) {
        int j = ni * 16 + (l & 15);
        p[ni] = (i < 92 && j < 92) ? __expf(s[ni] - m) : 0.f;
        sum += p[ni];
      }
      #pragma unroll
      for (int mm = 1; mm < 16; mm <<= 1) sum += __shfl_xor(sum, mm);
      float rs = (i < 92) ? (1.0f / sum) : 0.f;
      #pragma unroll
      for (int ni = 0; ni < 6; ++ni) attv[r][ni] = p[ni] * rs;
    }
    #pragma unroll
    for (int r = 0; r < 4; ++r) {
      int i = 16 * w + (l >> 4) * 4 + r;
      #pragma unroll
      for (int ni = 0; ni < 6; ++ni)
        e0a[i * 104 + ni * 16 + (l & 15)] = (_Float16)attv[r][ni];
    }
  }
  BAR_LGKM();   // att visible

  // ---- PV: out = att @ Wh + bias ; wave w: 2 passes of 32 f-cols
  #pragma unroll 1
  for (int pp = 0; pp < 2; ++pp) {
    int f0 = pp * 256 + w * 32;
    half8 bfp[3][2];
    #pragma unroll
    for (int ks = 0; ks < 3; ++ks)
      #pragma unroll
      for (int ni = 0; ni < 2; ++ni)
        bfp[ks][ni] = *(const half8*)((const char*)whT +
            (f0 + ni * 16 + (l & 15)) * 208 + ks * 64 + (l >> 4) * 16);
    f32x4 pz = {0.f, 0.f, 0.f, 0.f};
    f32x4 pacc[6][2];
    #pragma unroll
    for (int mi = 0; mi < 6; ++mi)
      #pragma unroll
      for (int ni = 0; ni < 2; ++ni) pacc[mi][ni] = pz;
    #pragma unroll
    for (int ks = 0; ks < 3; ++ks) {
      half8 af[6];
      #pragma unroll
      for (int mi = 0; mi < 6; ++mi)
        af[mi] = *(const half8*)((const char*)e0a +
                 (16 * mi + (l & 15)) * 208 + ks * 64 + (l >> 4) * 16);
      #pragma unroll
      for (int mi = 0; mi < 6; ++mi)
        #pragma unroll
        for (int ni = 0; ni < 2; ++ni)
          pacc[mi][ni] = __builtin_amdgcn_mfma_f32_16x16x32_f16(
              af[mi], bfp[ks][ni], pacc[mi][ni], 0, 0, 0);
    }
    #pragma unroll
    for (int ni = 0; ni < 2; ++ni) {
      int fcol = f0 + ni * 16 + (l & 15);
      float bv = bias[fcol];
      #pragma unroll
      for (int mi = 0; mi < 6; ++mi)
        #pragma unroll
        for (int r = 0; r < 4; ++r) {
          int i = 16 * mi + (l >> 4) * 4 + r;
          if (i < 92)
            out[((size_t)b * NNODE + i) * FOUT + fcol] = pacc[mi][ni][r] + bv;
        }
    }
  }
}

// ---------------------------------------------------------------------------
extern "C" void kernel_launch(void* const* d_in, const int* in_sizes, int n_in,
                              void* d_out, int out_size, void* d_ws, size_t ws_size,
                              hipStream_t stream) {
  (void)in_sizes; (void)n_in; (void)out_size; (void)ws_size;
  const float* X    = (const float*)d_in[0];
  const int*   adj  = (const int*)d_in[1];
  const float* W    = (const float*)d_in[2];
  const float* av   = (const float*)d_in[3];
  const float* Am   = (const float*)d_in[4];
  const float* bias = (const float*)d_in[5];
  float* out = (float*)d_out;
  char* ws = (char*)d_ws;

  _Float16* WT  = (_Float16*)(ws);              // 1,048,576 B
  _Float16* ATp = (_Float16*)(ws + 1048576);    //    19,968 B

  prep_kernel<<<68, 256, 0, stream>>>(W, Am, WT, ATp);
  hipFuncSetAttribute((const void*)fused_kernel,
                      hipFuncAttributeMaxDynamicSharedMemorySize, 157952);
  fused_kernel<<<1024, 512, 157952, stream>>>(X, WT, ATp, adj, av, bias, out);
}